// Round 3
// baseline (652.988 us; speedup 1.0000x reference)
//
#include <hip/hip_runtime.h>
#include <hip/hip_bf16.h>

typedef __hip_bfloat16 bf16;

#define BSHIFT 12
#define BWIDTH 4096          // nodes per bucket
#define CHUNK  8192          // records per accum block
#define NBMAX  32

// dtype-flexible scalar load: bf16 or f32 element i
__device__ __forceinline__ float ldf(const void* p, long i, bool isb) {
    return isb ? __bfloat162float(((const bf16*)p)[i]) : ((const float*)p)[i];
}

// HW fp32 atomic (global_atomic_add_f32, no CAS loop) — fallback path only.
__device__ __forceinline__ void atomAdd(float* p, float v) {
    unsafeAtomicAdd(p, v);
}

// Per-tensor input dtype detection.
// flags[0]: x bf16?  flags[1]: edge_attr bf16?  flags[2]: weights bf16?  flags[3]: idx int64?
__global__ void detect_kernel(const unsigned short* __restrict__ x16,
                              const unsigned short* __restrict__ ea16,
                              const unsigned short* __restrict__ we16,
                              const int* __restrict__ ei,
                              unsigned* __restrict__ flags)
{
    __shared__ int cnt[4];
    int t = threadIdx.x; // 256 threads
    if (t < 4) cnt[t] = 0;
    __syncthreads();
    auto sane = [](unsigned short u) { int ex = (u >> 7) & 0xFF; return ex >= 97 && ex <= 157; };
    if (sane(x16[t]))  atomicAdd(&cnt[0], 1);
    if (sane(ea16[t])) atomicAdd(&cnt[1], 1);
    if (t < 32 && sane(we16[t])) atomicAdd(&cnt[2], 1);
    if (t < 32 && ei[2 * t + 1] == 0) atomicAdd(&cnt[3], 1);
    __syncthreads();
    if (t == 0) {
        flags[0] = (cnt[0] >= 240) ? 1u : 0u;
        flags[1] = (cnt[1] >= 240) ? 1u : 0u;
        flags[2] = (cnt[2] >= 29) ? 1u : 0u;
        flags[3] = (cnt[3] == 32) ? 1u : 0u;
    }
}

// Histogram of dst buckets. Per-block LDS histogram -> <=NB global int atomics/block.
__global__ void count_kernel(const int* __restrict__ ei, int* __restrict__ hist,
                             const unsigned* __restrict__ flags, int E, int NB)
{
    __shared__ int h[NBMAX];
    int t = threadIdx.x;
    if (t < NB) h[t] = 0;
    __syncthreads();
    int e = blockIdx.x * blockDim.x + t;
    if (e < E) {
        const bool i64 = flags[3] != 0;
        size_t dw = i64 ? ((size_t)2 * E + 2 * (size_t)e) : ((size_t)E + e);
        int d = ei[dw];
        atomicAdd(&h[d >> BSHIFT], 1);
    }
    __syncthreads();
    if (t < NB && h[t] > 0) atomicAdd(&hist[t], h[t]);
}

// Prefix sums: record bases (cursor init) + chunk-region offsets.
__global__ void plan_kernel(const int* __restrict__ hist, int* __restrict__ cursor,
                            int* __restrict__ recBase, int* __restrict__ chunkOff, int NB)
{
    if (threadIdx.x == 0) {
        int rb = 0, co = 0;
        for (int b = 0; b < NB; ++b) {
            cursor[b]  = rb;
            recBase[b] = rb;
            chunkOff[b] = co;
            rb += hist[b];
            co += (hist[b] + CHUNK - 1) / CHUNK;
        }
        chunkOff[NB] = co;
    }
}

// Pass A (binned): pair_pred -> d_out, (ex,dst) -> tail,
// record (d_local, ex, ex*xs) scattered into dst bucket region. NO f32 atomics.
__global__ void passA_binned(const void* __restrict__ x, const int* __restrict__ ei,
                             const void* __restrict__ ea,
                             const void* __restrict__ W_node, const void* __restrict__ W_edge,
                             float2* __restrict__ out_pp, float2* __restrict__ tail,
                             float4* __restrict__ records, int* __restrict__ cursor,
                             const unsigned* __restrict__ flags, int E, int NB)
{
    __shared__ float wn[4];
    __shared__ float we[32];
    __shared__ int scnt[NBMAX];
    __shared__ int sbase[NBMAX];
    const bool fx = flags[0] != 0, fe = flags[1] != 0;
    const bool fw = flags[2] != 0, i64 = flags[3] != 0;
    int tid = threadIdx.x;
    if (tid < 4)  wn[tid] = ldf(W_node, tid, fw);
    if (tid < 32) we[tid] = ldf(W_edge, tid, fw);
    if (tid < NB) scnt[tid] = 0;
    __syncthreads();

    int e = blockIdx.x * blockDim.x + tid;
    const bool active = e < E;
    int d = 0;
    float xs = 0.f, ex = 0.f;

    if (active) {
        size_t sw = i64 ? (size_t)2 * e : (size_t)e;
        size_t dw = i64 ? ((size_t)2 * E + 2 * (size_t)e) : ((size_t)E + e);
        int s = ei[sw];
        d = ei[dw];

        xs = ldf(x, s, fx);
        float xd = ldf(x, d, fx);
        float l0 = xs * wn[0] + xd * wn[2];
        float l1 = xs * wn[1] + xd * wn[3];

        if (fe) {
            const uint4* p = (const uint4*)((const bf16*)ea + (size_t)e * 16);
            uint4 a = p[0], b = p[1];
            unsigned w[8] = {a.x, a.y, a.z, a.w, b.x, b.y, b.z, b.w};
#pragma unroll
            for (int k = 0; k < 8; ++k) {
                float lo = __uint_as_float(w[k] << 16);
                float hi = __uint_as_float(w[k] & 0xFFFF0000u);
                l0 += lo * we[4 * k + 0] + hi * we[4 * k + 2];
                l1 += lo * we[4 * k + 1] + hi * we[4 * k + 3];
            }
        } else {
            const float4* p = (const float4*)((const float*)ea + (size_t)e * 16);
#pragma unroll
            for (int q = 0; q < 4; ++q) {
                float4 v = p[q];
                l0 += v.x * we[8 * q + 0] + v.y * we[8 * q + 2] +
                      v.z * we[8 * q + 4] + v.w * we[8 * q + 6];
                l1 += v.x * we[8 * q + 1] + v.y * we[8 * q + 3] +
                      v.z * we[8 * q + 5] + v.w * we[8 * q + 7];
            }
        }

        float pp0 = l0 >= 0.f ? l0 : 0.2f * l0;  // leaky_relu(., 0.2)
        float pp1 = l1 >= 0.f ? l1 : 0.2f * l1;
        out_pp[e] = make_float2(pp0, pp1);

        float sc = fminf(pp0 - pp1, 80.f);
        ex = expf(sc);
        tail[e] = make_float2(ex, __int_as_float(d));
    }

    // block-local bucket grouping -> one cursor atomic per touched bucket
    int b = active ? (d >> BSHIFT) : 0;
    int rank = 0;
    if (active) rank = atomicAdd(&scnt[b], 1);
    __syncthreads();
    if (tid < NB && scnt[tid] > 0) sbase[tid] = atomicAdd(&cursor[tid], scnt[tid]);
    __syncthreads();
    if (active) {
        int dl = d & (BWIDTH - 1);
        records[(size_t)sbase[b] + rank] =
            make_float4(__int_as_float(dl), ex, ex * xs, 0.f);
    }
}

// Accumulate one chunk of one bucket in LDS, write dense partial. No global atomics.
__launch_bounds__(256)
__global__ void accum_kernel(const float4* __restrict__ records,
                             const int* __restrict__ hist,
                             const int* __restrict__ recBase,
                             const int* __restrict__ chunkOff,
                             float* __restrict__ rep)
{
    int b = blockIdx.y, c = blockIdx.x;
    int cnt = hist[b];
    int start = c * CHUNK;
    if (start >= cnt) return;
    int end = min(cnt, start + CHUNK);

    __shared__ float acc[2 * BWIDTH];  // den [0..BW), num [BW..2BW)
    for (int i = threadIdx.x; i < 2 * BWIDTH; i += 256) acc[i] = 0.f;
    __syncthreads();

    const float4* rec = records + recBase[b];
    for (int i = start + threadIdx.x; i < end; i += 256) {
        float4 r = rec[i];
        int dl = __float_as_int(r.x);
        atomicAdd(&acc[dl], r.y);           // ds_add_f32
        atomicAdd(&acc[BWIDTH + dl], r.z);
    }
    __syncthreads();

    float* out = rep + (size_t)(chunkOff[b] + c) * (2 * BWIDTH);
    const float4* a4 = (const float4*)acc;
    float4* o4 = (float4*)out;
    for (int i = threadIdx.x; i < (2 * BWIDTH) / 4; i += 256) o4[i] = a4[i];
}

// Sum per-bucket partials -> denom_tot + node output.
__global__ void reduce_binned(const float* __restrict__ rep,
                              const int* __restrict__ chunkOff,
                              float* __restrict__ denom_tot,
                              float* __restrict__ out_node,
                              const void* __restrict__ W,
                              const unsigned* __restrict__ flags, int N)
{
    int n = blockIdx.x * blockDim.x + threadIdx.x;
    if (n >= N) return;
    int b = n >> BSHIFT, loc = n & (BWIDTH - 1);
    int p0 = chunkOff[b], p1 = chunkOff[b + 1];
    float den = 0.f, num = 0.f;
    for (int p = p0; p < p1; ++p) {
        const float* base = rep + (size_t)p * (2 * BWIDTH);
        den += base[loc];
        num += base[BWIDTH + loc];
    }
    denom_tot[n] = den;
    float w0 = ldf(W, 0, flags[2] != 0);
    out_node[n] = w0 * num / (den + 1e-16f);
}

// ---------------- fallback path (atomic rep), used if ws too small ----------------
__global__ void passA_atomic(const void* __restrict__ x, const int* __restrict__ ei,
                             const void* __restrict__ ea,
                             const void* __restrict__ W_node, const void* __restrict__ W_edge,
                             float2* __restrict__ out_pp, float* __restrict__ tail,
                             float* __restrict__ rep,
                             const unsigned* __restrict__ flags,
                             int E, int N, int rmask, int packed)
{
    __shared__ float wn[4];
    __shared__ float we[32];
    const bool fx = flags[0] != 0, fe = flags[1] != 0;
    const bool fw = flags[2] != 0, i64 = flags[3] != 0;
    {
        int tt = threadIdx.x;
        if (tt < 4)  wn[tt] = ldf(W_node, tt, fw);
        if (tt < 32) we[tt] = ldf(W_edge, tt, fw);
    }
    __syncthreads();

    int e = blockIdx.x * blockDim.x + threadIdx.x;
    if (e >= E) return;

    size_t sw = i64 ? (size_t)2 * e : (size_t)e;
    size_t dw = i64 ? ((size_t)2 * E + 2 * (size_t)e) : ((size_t)E + e);
    int s = ei[sw], d = ei[dw];

    float xs = ldf(x, s, fx), xd = ldf(x, d, fx);
    float l0 = xs * wn[0] + xd * wn[2];
    float l1 = xs * wn[1] + xd * wn[3];

    if (fe) {
        const uint4* p = (const uint4*)((const bf16*)ea + (size_t)e * 16);
        uint4 a = p[0], b = p[1];
        unsigned w[8] = {a.x, a.y, a.z, a.w, b.x, b.y, b.z, b.w};
#pragma unroll
        for (int k = 0; k < 8; ++k) {
            float lo = __uint_as_float(w[k] << 16);
            float hi = __uint_as_float(w[k] & 0xFFFF0000u);
            l0 += lo * we[4 * k + 0] + hi * we[4 * k + 2];
            l1 += lo * we[4 * k + 1] + hi * we[4 * k + 3];
        }
    } else {
        const float4* p = (const float4*)((const float*)ea + (size_t)e * 16);
#pragma unroll
        for (int q = 0; q < 4; ++q) {
            float4 v = p[q];
            l0 += v.x * we[8 * q + 0] + v.y * we[8 * q + 2] +
                  v.z * we[8 * q + 4] + v.w * we[8 * q + 6];
            l1 += v.x * we[8 * q + 1] + v.y * we[8 * q + 3] +
                  v.z * we[8 * q + 5] + v.w * we[8 * q + 7];
        }
    }

    float pp0 = l0 >= 0.f ? l0 : 0.2f * l0;
    float pp1 = l1 >= 0.f ? l1 : 0.2f * l1;
    out_pp[e] = make_float2(pp0, pp1);

    float sc = fminf(pp0 - pp1, 80.f);
    float ex = expf(sc);

    if (packed) ((float2*)tail)[e] = make_float2(ex, __int_as_float(d));
    else        tail[e] = ex;

    float* base = rep + (size_t)((unsigned)blockIdx.x & (unsigned)rmask) * (size_t)2 * N;
    atomAdd(base + d,     ex);
    atomAdd(base + N + d, ex * xs);
}

__global__ void reduce_atomic(const float* __restrict__ rep,
                              float* __restrict__ denom_tot,
                              float* __restrict__ out_node,
                              const void* __restrict__ W,
                              const unsigned* __restrict__ flags,
                              int N, int R)
{
    int n = blockIdx.x * blockDim.x + threadIdx.x;
    if (n >= N) return;
    const bool fw = flags[2] != 0;
    float den = 0.f, num = 0.f;
    for (int r = 0; r < R; ++r) {
        den += rep[(size_t)r * 2 * N + n];
        num += rep[(size_t)r * 2 * N + N + n];
    }
    denom_tot[n] = den;
    float w0 = ldf(W, 0, fw);
    out_node[n] = w0 * num / (den + 1e-16f);
}

// Pass B (atomic-free): attn = ex / (denom_tot[dst] + 1e-16)
__global__ void passB_kernel(const int* __restrict__ ei,
                             const float* __restrict__ tail,
                             const float* __restrict__ denom_tot,
                             float* __restrict__ out_attn,
                             const unsigned* __restrict__ flags, int E, int packed)
{
    int e = blockIdx.x * blockDim.x + threadIdx.x;
    if (e >= E) return;
    if (packed) {
        float2 v = ((const float2*)tail)[e];
        int d = __float_as_int(v.y);
        out_attn[e] = v.x / (denom_tot[d] + 1e-16f);
    } else {
        const bool i64 = flags[3] != 0;
        size_t dw = i64 ? ((size_t)2 * E + 2 * (size_t)e) : ((size_t)E + e);
        int d = ei[dw];
        out_attn[e] = tail[e] / (denom_tot[d] + 1e-16f);
    }
}

extern "C" void kernel_launch(void* const* d_in, const int* in_sizes, int n_in,
                              void* d_out, int out_size, void* d_ws, size_t ws_size,
                              hipStream_t stream)
{
    const void* x      = d_in[0];
    const int*  ei     = (const int*)d_in[1];
    const void* ea     = d_in[2];
    const void* W      = d_in[3];
    const void* W_node = d_in[4];
    const void* W_edge = d_in[5];

    const int N = in_sizes[0];       // x is [N,1]
    const int E = in_sizes[1] / 2;   // edge_index is [2,E]

    float*  out_node = (float*)d_out;
    float*  out_attn = out_node + N;
    float2* out_pp   = (float2*)(out_attn + E);

    const int blk = 256;
    const int gE = (E + blk - 1) / blk;
    const int gN = (N + blk - 1) / blk;

    const int NB   = (N + BWIDTH - 1) >> BSHIFT;
    const int MAXC = (E + CHUNK - 1) / CHUNK;

    // binned ws layout:
    //   [0,16)    flags u32[4]
    //   [16,...)  hist i32[NBMAX] | cursor i32[NBMAX] | recBase i32[NBMAX] | chunkOff i32[NBMAX+1]
    //   @1024     denom_tot f32[N] | tail float2[E] | records float4[E] | rep f32[(MAXC+NB)*2*BWIDTH]
    size_t headerB = 1024;
    size_t denomB  = (size_t)N * 4;
    size_t tailB   = (size_t)E * 8;
    size_t recB    = (size_t)E * 16;
    size_t repB    = (size_t)(MAXC + NB) * (2 * BWIDTH) * 4;
    size_t need    = headerB + denomB + tailB + recB + repB;

    unsigned* flags = (unsigned*)d_ws;

    if (NB <= NBMAX && ws_size >= need) {
        int* hist     = (int*)((char*)d_ws + 16);
        int* cursor   = hist + NBMAX;
        int* recBase  = cursor + NBMAX;
        int* chunkOff = recBase + NBMAX;
        char* payload = (char*)d_ws + headerB;
        float*  denom_tot = (float*)payload;
        float2* tail      = (float2*)(payload + denomB);
        float4* records   = (float4*)(payload + denomB + tailB);
        float*  rep       = (float*)(payload + denomB + tailB + recB);

        hipMemsetAsync(hist, 0, NBMAX * sizeof(int), stream);
        detect_kernel<<<1, 256, 0, stream>>>((const unsigned short*)x,
                                             (const unsigned short*)ea,
                                             (const unsigned short*)W_edge, ei, flags);
        count_kernel<<<gE, blk, 0, stream>>>(ei, hist, flags, E, NB);
        plan_kernel<<<1, 64, 0, stream>>>(hist, cursor, recBase, chunkOff, NB);
        passA_binned<<<gE, blk, 0, stream>>>(x, ei, ea, W_node, W_edge,
                                             out_pp, tail, records, cursor,
                                             flags, E, NB);
        accum_kernel<<<dim3(MAXC, NB), blk, 0, stream>>>(records, hist, recBase,
                                                         chunkOff, rep);
        reduce_binned<<<gN, blk, 0, stream>>>(rep, chunkOff, denom_tot, out_node,
                                              W, flags, N);
        passB_kernel<<<gE, blk, 0, stream>>>(ei, (const float*)tail, denom_tot,
                                             out_attn, flags, E, 1);
    } else {
        // fallback: replica atomic path
        int R = 1, packed = 0;
        auto fixed = [&](int cand) {
            return (size_t)16 + (size_t)cand * 2 * N * 4 + (size_t)N * 4;
        };
        int chosen = 0;
        for (int cand = 16; cand >= 1; cand >>= 1)
            if (ws_size >= fixed(cand) + (size_t)E * 8) { chosen = cand; packed = 1; break; }
        if (!chosen)
            for (int cand = 16; cand >= 1; cand >>= 1)
                if (ws_size >= fixed(cand) + (size_t)E * 4) { chosen = cand; packed = 0; break; }
        R = chosen > 0 ? chosen : 1;
        const int rmask = R - 1;

        float* rep       = (float*)(flags + 4);
        float* denom_tot = rep + (size_t)R * 2 * N;
        float* tail      = denom_tot + N;

        hipMemsetAsync(rep, 0, (size_t)R * 2 * N * sizeof(float), stream);
        detect_kernel<<<1, 256, 0, stream>>>((const unsigned short*)x,
                                             (const unsigned short*)ea,
                                             (const unsigned short*)W_edge, ei, flags);
        passA_atomic<<<gE, blk, 0, stream>>>(x, ei, ea, W_node, W_edge,
                                             out_pp, tail, rep, flags,
                                             E, N, rmask, packed);
        reduce_atomic<<<gN, blk, 0, stream>>>(rep, denom_tot, out_node, W, flags, N, R);
        passB_kernel<<<gE, blk, 0, stream>>>(ei, tail, denom_tot, out_attn,
                                             flags, E, packed);
    }
}

// Round 4
// 427.718 us; speedup vs baseline: 1.5267x; 1.5267x over previous
//
#include <hip/hip_runtime.h>
#include <hip/hip_bf16.h>

typedef __hip_bfloat16 bf16;

// dtype-flexible scalar load: bf16 or f32 element i
__device__ __forceinline__ float ldf(const void* p, long i, bool isb) {
    return isb ? __bfloat162float(((const bf16*)p)[i]) : ((const float*)p)[i];
}

// f32 -> bf16 with round-to-nearest-even (bit-level, no header dependency)
__device__ __forceinline__ unsigned f2bf(float f) {
    unsigned u = __float_as_uint(f);
    return (u + 0x7FFFu + ((u >> 16) & 1u)) >> 16;
}

// Packed bf16x2 global atomic add: ONE memory-side atomic op carrying both
// accumulators (den in low half, num in high half). Halves the per-op cost
// vs two global_atomic_add_f32 (proven per-op-bound at ~20 G ops/s).
__device__ __forceinline__ void atomPkAddBf16(unsigned* p, unsigned packed) {
    asm volatile("global_atomic_pk_add_bf16 %0, %1, off"
                 :: "v"(p), "v"(packed) : "memory");
}

// f32 HW atomic — fallback path only.
__device__ __forceinline__ void atomAdd(float* p, float v) {
    unsafeAtomicAdd(p, v);
}

// Per-tensor input dtype detection.
// flags[0]: x bf16?  flags[1]: edge_attr bf16?  flags[2]: weights bf16?  flags[3]: idx int64?
__global__ void detect_kernel(const unsigned short* __restrict__ x16,
                              const unsigned short* __restrict__ ea16,
                              const unsigned short* __restrict__ we16,
                              const int* __restrict__ ei,
                              unsigned* __restrict__ flags)
{
    __shared__ int cnt[4];
    int t = threadIdx.x; // 256 threads
    if (t < 4) cnt[t] = 0;
    __syncthreads();
    auto sane = [](unsigned short u) { int ex = (u >> 7) & 0xFF; return ex >= 97 && ex <= 157; };
    if (sane(x16[t]))  atomicAdd(&cnt[0], 1);
    if (sane(ea16[t])) atomicAdd(&cnt[1], 1);
    if (t < 32 && sane(we16[t])) atomicAdd(&cnt[2], 1);
    if (t < 32 && ei[2 * t + 1] == 0) atomicAdd(&cnt[3], 1);
    __syncthreads();
    if (t == 0) {
        flags[0] = (cnt[0] >= 240) ? 1u : 0u;
        flags[1] = (cnt[1] >= 240) ? 1u : 0u;
        flags[2] = (cnt[2] >= 29) ? 1u : 0u;
        flags[3] = (cnt[3] == 32) ? 1u : 0u;
    }
}

// Pass A (single edge pass, ONE pk-bf16 atomic per edge):
//   pair_pred -> d_out (f32), (ex, dst) -> tail ws,
//   rep[r][d] +=pk (bf16(ex) | bf16(ex*xs)<<16), r = blockIdx & rmask.
// R=16 replicas keep per-replica chains short (~4 adds) so bf16 accumulation
// error stays ~0.5%; replicas are combined in f32 by reduce_kernel.
__global__ void passA_pk(const void* __restrict__ x, const int* __restrict__ ei,
                         const void* __restrict__ ea,
                         const void* __restrict__ W_node, const void* __restrict__ W_edge,
                         float2* __restrict__ out_pp, float2* __restrict__ tail,
                         unsigned* __restrict__ rep,
                         const unsigned* __restrict__ flags,
                         int E, int N, int rmask)
{
    __shared__ float wn[4];
    __shared__ float we[32];
    const bool fx = flags[0] != 0, fe = flags[1] != 0;
    const bool fw = flags[2] != 0, i64 = flags[3] != 0;
    {
        int tt = threadIdx.x;
        if (tt < 4)  wn[tt] = ldf(W_node, tt, fw);
        if (tt < 32) we[tt] = ldf(W_edge, tt, fw);
    }
    __syncthreads();

    int e = blockIdx.x * blockDim.x + threadIdx.x;
    if (e >= E) return;

    size_t sw = i64 ? (size_t)2 * e : (size_t)e;
    size_t dw = i64 ? ((size_t)2 * E + 2 * (size_t)e) : ((size_t)E + e);
    int s = ei[sw], d = ei[dw];

    float xs = ldf(x, s, fx), xd = ldf(x, d, fx);
    float l0 = xs * wn[0] + xd * wn[2];
    float l1 = xs * wn[1] + xd * wn[3];

    if (fe) {
        const uint4* p = (const uint4*)((const bf16*)ea + (size_t)e * 16);
        uint4 a = p[0], b = p[1];
        unsigned w[8] = {a.x, a.y, a.z, a.w, b.x, b.y, b.z, b.w};
#pragma unroll
        for (int k = 0; k < 8; ++k) {
            float lo = __uint_as_float(w[k] << 16);
            float hi = __uint_as_float(w[k] & 0xFFFF0000u);
            l0 += lo * we[4 * k + 0] + hi * we[4 * k + 2];
            l1 += lo * we[4 * k + 1] + hi * we[4 * k + 3];
        }
    } else {
        const float4* p = (const float4*)((const float*)ea + (size_t)e * 16);
#pragma unroll
        for (int q = 0; q < 4; ++q) {
            float4 v = p[q];
            l0 += v.x * we[8 * q + 0] + v.y * we[8 * q + 2] +
                  v.z * we[8 * q + 4] + v.w * we[8 * q + 6];
            l1 += v.x * we[8 * q + 1] + v.y * we[8 * q + 3] +
                  v.z * we[8 * q + 5] + v.w * we[8 * q + 7];
        }
    }

    float pp0 = l0 >= 0.f ? l0 : 0.2f * l0;  // leaky_relu(., 0.2)
    float pp1 = l1 >= 0.f ? l1 : 0.2f * l1;
    out_pp[e] = make_float2(pp0, pp1);

    float sc = fminf(pp0 - pp1, 80.f);   // clamp only guards f32 exp overflow
    float ex = expf(sc);
    tail[e] = make_float2(ex, __int_as_float(d));

    unsigned packed = f2bf(ex) | (f2bf(ex * xs) << 16);
    unsigned* myrep = rep + (size_t)((unsigned)blockIdx.x & (unsigned)rmask) * N;
    atomPkAddBf16(myrep + d, packed);    // ONE atomic per edge
}

// Reduce replicas (bf16x2 -> f32 sums) -> denom_tot + node output.
__global__ void reduce_pk(const unsigned* __restrict__ rep,
                          float* __restrict__ denom_tot,
                          float* __restrict__ out_node,
                          const void* __restrict__ W,
                          const unsigned* __restrict__ flags,
                          int N, int R)
{
    int n = blockIdx.x * blockDim.x + threadIdx.x;
    if (n >= N) return;
    float den = 0.f, num = 0.f;
    for (int r = 0; r < R; ++r) {
        unsigned v = rep[(size_t)r * N + n];
        den += __uint_as_float(v << 16);          // low bf16  = ex sum
        num += __uint_as_float(v & 0xFFFF0000u);  // high bf16 = ex*xs sum
    }
    denom_tot[n] = den;
    float w0 = ldf(W, 0, flags[2] != 0);
    out_node[n] = w0 * num / (den + 1e-16f);
}

// ---------------- fallback path (f32 atomic rep), used if ws too small ----------------
__global__ void passA_atomic(const void* __restrict__ x, const int* __restrict__ ei,
                             const void* __restrict__ ea,
                             const void* __restrict__ W_node, const void* __restrict__ W_edge,
                             float2* __restrict__ out_pp, float* __restrict__ tail,
                             float* __restrict__ rep,
                             const unsigned* __restrict__ flags,
                             int E, int N, int rmask, int packed)
{
    __shared__ float wn[4];
    __shared__ float we[32];
    const bool fx = flags[0] != 0, fe = flags[1] != 0;
    const bool fw = flags[2] != 0, i64 = flags[3] != 0;
    {
        int tt = threadIdx.x;
        if (tt < 4)  wn[tt] = ldf(W_node, tt, fw);
        if (tt < 32) we[tt] = ldf(W_edge, tt, fw);
    }
    __syncthreads();

    int e = blockIdx.x * blockDim.x + threadIdx.x;
    if (e >= E) return;

    size_t sw = i64 ? (size_t)2 * e : (size_t)e;
    size_t dw = i64 ? ((size_t)2 * E + 2 * (size_t)e) : ((size_t)E + e);
    int s = ei[sw], d = ei[dw];

    float xs = ldf(x, s, fx), xd = ldf(x, d, fx);
    float l0 = xs * wn[0] + xd * wn[2];
    float l1 = xs * wn[1] + xd * wn[3];

    if (fe) {
        const uint4* p = (const uint4*)((const bf16*)ea + (size_t)e * 16);
        uint4 a = p[0], b = p[1];
        unsigned w[8] = {a.x, a.y, a.z, a.w, b.x, b.y, b.z, b.w};
#pragma unroll
        for (int k = 0; k < 8; ++k) {
            float lo = __uint_as_float(w[k] << 16);
            float hi = __uint_as_float(w[k] & 0xFFFF0000u);
            l0 += lo * we[4 * k + 0] + hi * we[4 * k + 2];
            l1 += lo * we[4 * k + 1] + hi * we[4 * k + 3];
        }
    } else {
        const float4* p = (const float4*)((const float*)ea + (size_t)e * 16);
#pragma unroll
        for (int q = 0; q < 4; ++q) {
            float4 v = p[q];
            l0 += v.x * we[8 * q + 0] + v.y * we[8 * q + 2] +
                  v.z * we[8 * q + 4] + v.w * we[8 * q + 6];
            l1 += v.x * we[8 * q + 1] + v.y * we[8 * q + 3] +
                  v.z * we[8 * q + 5] + v.w * we[8 * q + 7];
        }
    }

    float pp0 = l0 >= 0.f ? l0 : 0.2f * l0;
    float pp1 = l1 >= 0.f ? l1 : 0.2f * l1;
    out_pp[e] = make_float2(pp0, pp1);

    float sc = fminf(pp0 - pp1, 80.f);
    float ex = expf(sc);

    if (packed) ((float2*)tail)[e] = make_float2(ex, __int_as_float(d));
    else        tail[e] = ex;

    float* base = rep + (size_t)((unsigned)blockIdx.x & (unsigned)rmask) * (size_t)2 * N;
    atomAdd(base + d,     ex);
    atomAdd(base + N + d, ex * xs);
}

__global__ void reduce_atomic(const float* __restrict__ rep,
                              float* __restrict__ denom_tot,
                              float* __restrict__ out_node,
                              const void* __restrict__ W,
                              const unsigned* __restrict__ flags,
                              int N, int R)
{
    int n = blockIdx.x * blockDim.x + threadIdx.x;
    if (n >= N) return;
    const bool fw = flags[2] != 0;
    float den = 0.f, num = 0.f;
    for (int r = 0; r < R; ++r) {
        den += rep[(size_t)r * 2 * N + n];
        num += rep[(size_t)r * 2 * N + N + n];
    }
    denom_tot[n] = den;
    float w0 = ldf(W, 0, fw);
    out_node[n] = w0 * num / (den + 1e-16f);
}

// Pass B (atomic-free): attn = ex / (denom_tot[dst] + 1e-16)
__global__ void passB_kernel(const int* __restrict__ ei,
                             const float* __restrict__ tail,
                             const float* __restrict__ denom_tot,
                             float* __restrict__ out_attn,
                             const unsigned* __restrict__ flags, int E, int packed)
{
    int e = blockIdx.x * blockDim.x + threadIdx.x;
    if (e >= E) return;
    if (packed) {
        float2 v = ((const float2*)tail)[e];
        int d = __float_as_int(v.y);
        out_attn[e] = v.x / (denom_tot[d] + 1e-16f);
    } else {
        const bool i64 = flags[3] != 0;
        size_t dw = i64 ? ((size_t)2 * E + 2 * (size_t)e) : ((size_t)E + e);
        int d = ei[dw];
        out_attn[e] = tail[e] / (denom_tot[d] + 1e-16f);
    }
}

extern "C" void kernel_launch(void* const* d_in, const int* in_sizes, int n_in,
                              void* d_out, int out_size, void* d_ws, size_t ws_size,
                              hipStream_t stream)
{
    const void* x      = d_in[0];
    const int*  ei     = (const int*)d_in[1];
    const void* ea     = d_in[2];
    const void* W      = d_in[3];
    const void* W_node = d_in[4];
    const void* W_edge = d_in[5];

    const int N = in_sizes[0];       // x is [N,1]
    const int E = in_sizes[1] / 2;   // edge_index is [2,E]

    float*  out_node = (float*)d_out;
    float*  out_attn = out_node + N;
    float2* out_pp   = (float2*)(out_attn + E);

    const int blk = 256;
    const int gE = (E + blk - 1) / blk;
    const int gN = (N + blk - 1) / blk;

    unsigned* flags = (unsigned*)d_ws;

    // pk path ws layout: flags[4] | rep u32[R*N] | denom_tot f32[N] | tail float2[E]
    const int Rpk = 16;
    size_t needPk = 16 + (size_t)Rpk * N * 4 + (size_t)N * 4 + (size_t)E * 8;

    if (ws_size >= needPk) {
        unsigned* rep       = (unsigned*)(flags + 4);
        float*    denom_tot = (float*)(rep + (size_t)Rpk * N);
        float2*   tail      = (float2*)(denom_tot + N);

        hipMemsetAsync(rep, 0, (size_t)Rpk * N * sizeof(unsigned), stream);
        detect_kernel<<<1, 256, 0, stream>>>((const unsigned short*)x,
                                             (const unsigned short*)ea,
                                             (const unsigned short*)W_edge, ei, flags);
        passA_pk<<<gE, blk, 0, stream>>>(x, ei, ea, W_node, W_edge,
                                         out_pp, tail, rep, flags,
                                         E, N, Rpk - 1);
        reduce_pk<<<gN, blk, 0, stream>>>(rep, denom_tot, out_node, W, flags, N, Rpk);
        passB_kernel<<<gE, blk, 0, stream>>>(ei, (const float*)tail, denom_tot,
                                             out_attn, flags, E, 1);
    } else {
        // fallback: f32 replica atomic path
        int R = 1, packed = 0;
        auto fixed = [&](int cand) {
            return (size_t)16 + (size_t)cand * 2 * N * 4 + (size_t)N * 4;
        };
        int chosen = 0;
        for (int cand = 16; cand >= 1; cand >>= 1)
            if (ws_size >= fixed(cand) + (size_t)E * 8) { chosen = cand; packed = 1; break; }
        if (!chosen)
            for (int cand = 16; cand >= 1; cand >>= 1)
                if (ws_size >= fixed(cand) + (size_t)E * 4) { chosen = cand; packed = 0; break; }
        R = chosen > 0 ? chosen : 1;
        const int rmask = R - 1;

        float* rep       = (float*)(flags + 4);
        float* denom_tot = rep + (size_t)R * 2 * N;
        float* tail      = denom_tot + N;

        hipMemsetAsync(rep, 0, (size_t)R * 2 * N * sizeof(float), stream);
        detect_kernel<<<1, 256, 0, stream>>>((const unsigned short*)x,
                                             (const unsigned short*)ea,
                                             (const unsigned short*)W_edge, ei, flags);
        passA_atomic<<<gE, blk, 0, stream>>>(x, ei, ea, W_node, W_edge,
                                             out_pp, tail, rep, flags,
                                             E, N, rmask, packed);
        reduce_atomic<<<gN, blk, 0, stream>>>(rep, denom_tot, out_node, W, flags, N, R);
        passB_kernel<<<gE, blk, 0, stream>>>(ei, tail, denom_tot, out_attn,
                                             flags, E, packed);
    }
}

// Round 6
// 425.136 us; speedup vs baseline: 1.5360x; 1.0061x over previous
//
#include <hip/hip_runtime.h>
#include <hip/hip_bf16.h>

typedef __hip_bfloat16 bf16;
typedef float f32x2 __attribute__((ext_vector_type(2)));   // NT-store-compatible

// dtype-flexible scalar load: bf16 or f32 element i
__device__ __forceinline__ float ldf(const void* p, long i, bool isb) {
    return isb ? __bfloat162float(((const bf16*)p)[i]) : ((const float*)p)[i];
}

// f32 -> bf16 with round-to-nearest-even (bit-level, no header dependency)
__device__ __forceinline__ unsigned f2bf(float f) {
    unsigned u = __float_as_uint(f);
    return (u + 0x7FFFu + ((u >> 16) & 1u)) >> 16;
}

// Packed bf16x2 global atomic add: ONE memory-side atomic op carrying both
// accumulators (den low half, num high half). Memory-side atomic ceiling is
// ~19.6 G ops/s per-op (measured r0-r4, invariant to scope/address), so one
// op per edge is the algorithmic floor for scatter accumulation.
__device__ __forceinline__ void atomPkAddBf16(unsigned* p, unsigned packed) {
    asm volatile("global_atomic_pk_add_bf16 %0, %1, off"
                 :: "v"(p), "v"(packed) : "memory");
}

// f32 HW atomic — fallback path only.
__device__ __forceinline__ void atomAdd(float* p, float v) {
    unsafeAtomicAdd(p, v);
}

// Per-block inline dtype detection (replaces the detect dispatch).
// Reads are identical across blocks -> L2-hot broadcast, ~negligible cost.
// Requires blockDim.x >= 256.
__device__ __forceinline__ void detectFlags(const unsigned short* __restrict__ x16,
                                            const unsigned short* __restrict__ ea16,
                                            const unsigned short* __restrict__ we16,
                                            const int* __restrict__ ei,
                                            bool& fx, bool& fe, bool& fw, bool& i64)
{
    __shared__ int cnt[4];
    int t = threadIdx.x;
    if (t < 4) cnt[t] = 0;
    __syncthreads();
    auto sane = [](unsigned short u) { int ex = (u >> 7) & 0xFF; return ex >= 97 && ex <= 157; };
    if (t < 256) {
        if (sane(x16[t]))  atomicAdd(&cnt[0], 1);
        if (sane(ea16[t])) atomicAdd(&cnt[1], 1);
        if (t < 32 && sane(we16[t])) atomicAdd(&cnt[2], 1);
        if (t < 32 && ei[2 * t + 1] == 0) atomicAdd(&cnt[3], 1);
    }
    __syncthreads();
    fx  = cnt[0] >= 240;
    fe  = cnt[1] >= 240;
    fw  = cnt[2] >= 29;
    i64 = cnt[3] == 32;
}

// Pass A (single edge pass, ONE pk-bf16 atomic per edge):
//   pair_pred -> d_out (f32, NT store), (ex, dst) -> tail ws,
//   rep[r][d] +=pk (bf16(ex) | bf16(ex*xs)<<16), r = blockIdx & 15.
// 16 replicas keep bf16 accumulation chains ~4 adds; combined in f32 later.
__global__ __launch_bounds__(256)
void passA_pk(const void* __restrict__ x, const int* __restrict__ ei,
              const void* __restrict__ ea,
              const void* __restrict__ W_node, const void* __restrict__ W_edge,
              float2* __restrict__ out_pp, float2* __restrict__ tail,
              unsigned* __restrict__ rep,
              int E, int N, int rmask)
{
    __shared__ float wn[4];
    __shared__ float we[32];
    bool fx, fe, fw, i64;
    detectFlags((const unsigned short*)x, (const unsigned short*)ea,
                (const unsigned short*)W_edge, ei, fx, fe, fw, i64);
    {
        int tt = threadIdx.x;
        if (tt < 4)  wn[tt] = ldf(W_node, tt, fw);
        if (tt < 32) we[tt] = ldf(W_edge, tt, fw);
    }
    __syncthreads();

    int e = blockIdx.x * blockDim.x + threadIdx.x;
    if (e >= E) return;

    size_t sw = i64 ? (size_t)2 * e : (size_t)e;
    size_t dw = i64 ? ((size_t)2 * E + 2 * (size_t)e) : ((size_t)E + e);
    int s = ei[sw], d = ei[dw];

    float xs = ldf(x, s, fx), xd = ldf(x, d, fx);
    float l0 = xs * wn[0] + xd * wn[2];
    float l1 = xs * wn[1] + xd * wn[3];

    if (fe) {
        const uint4* p = (const uint4*)((const bf16*)ea + (size_t)e * 16);
        uint4 a = p[0], b = p[1];
        unsigned w[8] = {a.x, a.y, a.z, a.w, b.x, b.y, b.z, b.w};
#pragma unroll
        for (int k = 0; k < 8; ++k) {
            float lo = __uint_as_float(w[k] << 16);
            float hi = __uint_as_float(w[k] & 0xFFFF0000u);
            l0 += lo * we[4 * k + 0] + hi * we[4 * k + 2];
            l1 += lo * we[4 * k + 1] + hi * we[4 * k + 3];
        }
    } else {
        const float4* p = (const float4*)((const float*)ea + (size_t)e * 16);
#pragma unroll
        for (int q = 0; q < 4; ++q) {
            float4 v = p[q];
            l0 += v.x * we[8 * q + 0] + v.y * we[8 * q + 2] +
                  v.z * we[8 * q + 4] + v.w * we[8 * q + 6];
            l1 += v.x * we[8 * q + 1] + v.y * we[8 * q + 3] +
                  v.z * we[8 * q + 5] + v.w * we[8 * q + 7];
        }
    }

    float pp0 = l0 >= 0.f ? l0 : 0.2f * l0;  // leaky_relu(., 0.2)
    float pp1 = l1 >= 0.f ? l1 : 0.2f * l1;
    {
        f32x2 pp; pp.x = pp0; pp.y = pp1;
        __builtin_nontemporal_store(pp, (f32x2*)&out_pp[e]);   // pure output
    }

    float sc = fminf(pp0 - pp1, 80.f);   // clamp only guards f32 exp overflow
    float ex = expf(sc);
    tail[e] = make_float2(ex, __int_as_float(d));   // re-read by passB: cacheable

    unsigned packed = f2bf(ex) | (f2bf(ex * xs) << 16);
    unsigned* myrep = rep + (size_t)((unsigned)blockIdx.x & (unsigned)rmask) * N;
    atomPkAddBf16(myrep + d, packed);    // ONE atomic per edge
}

// Reduce replicas (bf16x2 -> f32 sums) -> denom_tot + node output.
// Vectorized: 4 nodes per thread, uint4 replica loads, float4 stores.
__global__ __launch_bounds__(256)
void reduce_pk(const unsigned* __restrict__ rep,
               float* __restrict__ denom_tot,
               float* __restrict__ out_node,
               const void* __restrict__ W,
               const void* __restrict__ x, const void* __restrict__ ea,
               const void* __restrict__ W_edge, const int* __restrict__ ei,
               int N, int R)
{
    bool fx, fe, fw, i64;
    detectFlags((const unsigned short*)x, (const unsigned short*)ea,
                (const unsigned short*)W_edge, ei, fx, fe, fw, i64);
    (void)fx; (void)fe; (void)i64;

    int i = blockIdx.x * blockDim.x + threadIdx.x;   // quad index
    int n0 = 4 * i;
    if (n0 >= N) return;
    float w0 = ldf(W, 0, fw);

    if (n0 + 3 < N) {
        float den[4] = {0.f, 0.f, 0.f, 0.f};
        float num[4] = {0.f, 0.f, 0.f, 0.f};
        for (int r = 0; r < R; ++r) {
            uint4 v = *(const uint4*)(rep + (size_t)r * N + n0);
            unsigned vv[4] = {v.x, v.y, v.z, v.w};
#pragma unroll
            for (int j = 0; j < 4; ++j) {
                den[j] += __uint_as_float(vv[j] << 16);
                num[j] += __uint_as_float(vv[j] & 0xFFFF0000u);
            }
        }
        *(float4*)(denom_tot + n0) = make_float4(den[0], den[1], den[2], den[3]);
        float4 o;
        o.x = w0 * num[0] / (den[0] + 1e-16f);
        o.y = w0 * num[1] / (den[1] + 1e-16f);
        o.z = w0 * num[2] / (den[2] + 1e-16f);
        o.w = w0 * num[3] / (den[3] + 1e-16f);
        *(float4*)(out_node + n0) = o;
    } else {
        for (int n = n0; n < N; ++n) {
            float den = 0.f, num = 0.f;
            for (int r = 0; r < R; ++r) {
                unsigned v = rep[(size_t)r * N + n];
                den += __uint_as_float(v << 16);
                num += __uint_as_float(v & 0xFFFF0000u);
            }
            denom_tot[n] = den;
            out_node[n] = w0 * num / (den + 1e-16f);
        }
    }
}

// Pass B (atomic-free, flag-free in packed mode): attn = ex / (denom[dst]+1e-16)
__global__ __launch_bounds__(256)
void passB_pk(const float2* __restrict__ tail,
              const float* __restrict__ denom_tot,
              float* __restrict__ out_attn, int E)
{
    int e = blockIdx.x * blockDim.x + threadIdx.x;
    if (e >= E) return;
    float2 v = tail[e];
    int d = __float_as_int(v.y);
    float a = v.x / (denom_tot[d] + 1e-16f);
    __builtin_nontemporal_store(a, &out_attn[e]);   // pure output (plain float: OK)
}

// ---------------- fallback path (f32 atomic rep), used if ws too small ----------------
__global__ void detect_kernel(const unsigned short* __restrict__ x16,
                              const unsigned short* __restrict__ ea16,
                              const unsigned short* __restrict__ we16,
                              const int* __restrict__ ei,
                              unsigned* __restrict__ flags)
{
    __shared__ int cnt[4];
    int t = threadIdx.x;
    if (t < 4) cnt[t] = 0;
    __syncthreads();
    auto sane = [](unsigned short u) { int ex = (u >> 7) & 0xFF; return ex >= 97 && ex <= 157; };
    if (sane(x16[t]))  atomicAdd(&cnt[0], 1);
    if (sane(ea16[t])) atomicAdd(&cnt[1], 1);
    if (t < 32 && sane(we16[t])) atomicAdd(&cnt[2], 1);
    if (t < 32 && ei[2 * t + 1] == 0) atomicAdd(&cnt[3], 1);
    __syncthreads();
    if (t == 0) {
        flags[0] = (cnt[0] >= 240) ? 1u : 0u;
        flags[1] = (cnt[1] >= 240) ? 1u : 0u;
        flags[2] = (cnt[2] >= 29) ? 1u : 0u;
        flags[3] = (cnt[3] == 32) ? 1u : 0u;
    }
}

__global__ void passA_atomic(const void* __restrict__ x, const int* __restrict__ ei,
                             const void* __restrict__ ea,
                             const void* __restrict__ W_node, const void* __restrict__ W_edge,
                             float2* __restrict__ out_pp, float* __restrict__ tail,
                             float* __restrict__ rep,
                             const unsigned* __restrict__ flags,
                             int E, int N, int rmask, int packed)
{
    __shared__ float wn[4];
    __shared__ float we[32];
    const bool fx = flags[0] != 0, fe = flags[1] != 0;
    const bool fw = flags[2] != 0, i64 = flags[3] != 0;
    {
        int tt = threadIdx.x;
        if (tt < 4)  wn[tt] = ldf(W_node, tt, fw);
        if (tt < 32) we[tt] = ldf(W_edge, tt, fw);
    }
    __syncthreads();

    int e = blockIdx.x * blockDim.x + threadIdx.x;
    if (e >= E) return;

    size_t sw = i64 ? (size_t)2 * e : (size_t)e;
    size_t dw = i64 ? ((size_t)2 * E + 2 * (size_t)e) : ((size_t)E + e);
    int s = ei[sw], d = ei[dw];

    float xs = ldf(x, s, fx), xd = ldf(x, d, fx);
    float l0 = xs * wn[0] + xd * wn[2];
    float l1 = xs * wn[1] + xd * wn[3];

    if (fe) {
        const uint4* p = (const uint4*)((const bf16*)ea + (size_t)e * 16);
        uint4 a = p[0], b = p[1];
        unsigned w[8] = {a.x, a.y, a.z, a.w, b.x, b.y, b.z, b.w};
#pragma unroll
        for (int k = 0; k < 8; ++k) {
            float lo = __uint_as_float(w[k] << 16);
            float hi = __uint_as_float(w[k] & 0xFFFF0000u);
            l0 += lo * we[4 * k + 0] + hi * we[4 * k + 2];
            l1 += lo * we[4 * k + 1] + hi * we[4 * k + 3];
        }
    } else {
        const float4* p = (const float4*)((const float*)ea + (size_t)e * 16);
#pragma unroll
        for (int q = 0; q < 4; ++q) {
            float4 v = p[q];
            l0 += v.x * we[8 * q + 0] + v.y * we[8 * q + 2] +
                  v.z * we[8 * q + 4] + v.w * we[8 * q + 6];
            l1 += v.x * we[8 * q + 1] + v.y * we[8 * q + 3] +
                  v.z * we[8 * q + 5] + v.w * we[8 * q + 7];
        }
    }

    float pp0 = l0 >= 0.f ? l0 : 0.2f * l0;
    float pp1 = l1 >= 0.f ? l1 : 0.2f * l1;
    out_pp[e] = make_float2(pp0, pp1);

    float sc = fminf(pp0 - pp1, 80.f);
    float ex = expf(sc);

    if (packed) ((float2*)tail)[e] = make_float2(ex, __int_as_float(d));
    else        tail[e] = ex;

    float* base = rep + (size_t)((unsigned)blockIdx.x & (unsigned)rmask) * (size_t)2 * N;
    atomAdd(base + d,     ex);
    atomAdd(base + N + d, ex * xs);
}

__global__ void reduce_atomic(const float* __restrict__ rep,
                              float* __restrict__ denom_tot,
                              float* __restrict__ out_node,
                              const void* __restrict__ W,
                              const unsigned* __restrict__ flags,
                              int N, int R)
{
    int n = blockIdx.x * blockDim.x + threadIdx.x;
    if (n >= N) return;
    const bool fw = flags[2] != 0;
    float den = 0.f, num = 0.f;
    for (int r = 0; r < R; ++r) {
        den += rep[(size_t)r * 2 * N + n];
        num += rep[(size_t)r * 2 * N + N + n];
    }
    denom_tot[n] = den;
    float w0 = ldf(W, 0, fw);
    out_node[n] = w0 * num / (den + 1e-16f);
}

__global__ void passB_kernel(const int* __restrict__ ei,
                             const float* __restrict__ tail,
                             const float* __restrict__ denom_tot,
                             float* __restrict__ out_attn,
                             const unsigned* __restrict__ flags, int E, int packed)
{
    int e = blockIdx.x * blockDim.x + threadIdx.x;
    if (e >= E) return;
    if (packed) {
        float2 v = ((const float2*)tail)[e];
        int d = __float_as_int(v.y);
        out_attn[e] = v.x / (denom_tot[d] + 1e-16f);
    } else {
        const bool i64 = flags[3] != 0;
        size_t dw = i64 ? ((size_t)2 * E + 2 * (size_t)e) : ((size_t)E + e);
        int d = ei[dw];
        out_attn[e] = tail[e] / (denom_tot[d] + 1e-16f);
    }
}

extern "C" void kernel_launch(void* const* d_in, const int* in_sizes, int n_in,
                              void* d_out, int out_size, void* d_ws, size_t ws_size,
                              hipStream_t stream)
{
    const void* x      = d_in[0];
    const int*  ei     = (const int*)d_in[1];
    const void* ea     = d_in[2];
    const void* W      = d_in[3];
    const void* W_node = d_in[4];
    const void* W_edge = d_in[5];

    const int N = in_sizes[0];       // x is [N,1]
    const int E = in_sizes[1] / 2;   // edge_index is [2,E]

    float*  out_node = (float*)d_out;
    float*  out_attn = out_node + N;
    float2* out_pp   = (float2*)(out_attn + E);

    const int blk = 256;
    const int gE = (E + blk - 1) / blk;

    unsigned* flags = (unsigned*)d_ws;

    // pk path ws layout: pad[4] u32 | rep u32[R*N] | denom_tot f32[N] | tail float2[E]
    const int Rpk = 16;
    size_t needPk = 16 + (size_t)Rpk * N * 4 + (size_t)N * 4 + (size_t)E * 8;

    if (ws_size >= needPk) {
        unsigned* rep       = (unsigned*)(flags + 4);
        float*    denom_tot = (float*)(rep + (size_t)Rpk * N);
        float2*   tail      = (float2*)(denom_tot + N);

        const int gN4 = ((N + 3) / 4 + blk - 1) / blk;

        (void)hipMemsetAsync(rep, 0, (size_t)Rpk * N * sizeof(unsigned), stream);
        passA_pk<<<gE, blk, 0, stream>>>(x, ei, ea, W_node, W_edge,
                                         out_pp, tail, rep, E, N, Rpk - 1);
        reduce_pk<<<gN4, blk, 0, stream>>>(rep, denom_tot, out_node, W,
                                           x, ea, W_edge, ei, N, Rpk);
        passB_pk<<<gE, blk, 0, stream>>>(tail, denom_tot, out_attn, E);
    } else {
        // fallback: f32 replica atomic path
        const int gN = (N + blk - 1) / blk;
        int R = 1, packed = 0;
        auto fixed = [&](int cand) {
            return (size_t)16 + (size_t)cand * 2 * N * 4 + (size_t)N * 4;
        };
        int chosen = 0;
        for (int cand = 16; cand >= 1; cand >>= 1)
            if (ws_size >= fixed(cand) + (size_t)E * 8) { chosen = cand; packed = 1; break; }
        if (!chosen)
            for (int cand = 16; cand >= 1; cand >>= 1)
                if (ws_size >= fixed(cand) + (size_t)E * 4) { chosen = cand; packed = 0; break; }
        R = chosen > 0 ? chosen : 1;
        const int rmask = R - 1;

        float* rep       = (float*)(flags + 4);
        float* denom_tot = rep + (size_t)R * 2 * N;
        float* tail      = denom_tot + N;

        (void)hipMemsetAsync(rep, 0, (size_t)R * 2 * N * sizeof(float), stream);
        detect_kernel<<<1, 256, 0, stream>>>((const unsigned short*)x,
                                             (const unsigned short*)ea,
                                             (const unsigned short*)W_edge, ei, flags);
        passA_atomic<<<gE, blk, 0, stream>>>(x, ei, ea, W_node, W_edge,
                                             out_pp, tail, rep, flags,
                                             E, N, rmask, packed);
        reduce_atomic<<<gN, blk, 0, stream>>>(rep, denom_tot, out_node, W, flags, N, R);
        passB_kernel<<<gE, blk, 0, stream>>>(ei, tail, denom_tot, out_attn,
                                             flags, E, packed);
    }
}